// Round 3
// baseline (3260.152 us; speedup 1.0000x reference)
//
#include <hip/hip_runtime.h>
#include <hip/hip_fp16.h>

#define EPS 1e-5f

typedef _Float16 f16x8 __attribute__((ext_vector_type(8)));
typedef float f32x4 __attribute__((ext_vector_type(4)));

// ---- ws layout (halfs), identical footprint to R2: 158,818,304 B ----
#define WFH_OFF 0ull
#define W2H_OFF 7929856ull          // 64 x 576
#define W3H_OFF 7966720ull          // 128 x 576
#define H3_OFF  8040448ull          // 1152 x 61952

// ---------------- prep: fp32 -> fp16 weight repacks ----------------
__global__ __launch_bounds__(256)
void k_prep(const float* __restrict__ w2, const float* __restrict__ w3,
            const float* __restrict__ wf, __half* __restrict__ ws)
{
    const int i = blockIdx.x * 256 + threadIdx.x;
    if (i < 6195200) {                       // wfh[o][pix*128+co] = wf[o][co*484+pix]
        const int o = i / 61952, k = i - o * 61952;
        const int co = k & 127, pix = k >> 7;
        ws[WFH_OFF + (size_t)o * 61952 + k] =
            __float2half(wf[(size_t)o * 61952 + co * 484 + pix]);
    } else if (i < 6195200 + 36864) {        // w2h[co][tap*64+ci]
        const int j = i - 6195200;
        const int co = j / 576, k = j - co * 576;
        const int tap = k >> 6, ci = k & 63;
        ws[W2H_OFF + j] = __float2half(w2[co * 576 + ci * 9 + tap]);
    } else if (i < 6195200 + 36864 + 73728) { // w3h[co][tap*64+ci]
        const int j = i - (6195200 + 36864);
        const int co = j / 576, k = j - co * 576;
        const int tap = k >> 6, ci = k & 63;
        ws[W3H_OFF + j] = __float2half(w3[co * 576 + ci * 9 + tap]);
    }
}

// 64-B LDS rows (32 fp16), 16B-granule XOR swizzle on (row&3)
__device__ __forceinline__ int lds64(int row, int colByte) {
    return row * 64 + (colByte ^ ((row & 3) << 4));
}

__device__ __forceinline__ uint32_t pk2(float a, float b) {
    __half2 h = __halves2half2(__float2half(a), __float2half(b));
    return *reinterpret_cast<uint32_t*>(&h);
}

// ---------------- fused conv1 -> conv2 -> conv3, half-patch blocks ----------------
// block = (patch, half): conv3 out rows base3..base3+10 (base3 = 11*half)
// LDS: patch x-slice 17x28 f32 (1904 B) + act region 390 rows x 64 B (24960 B) = 26864 B
__global__ __launch_bounds__(512, 8)
void k_conv123(const float* __restrict__ x,
               const float* __restrict__ w1, const float* __restrict__ b1,
               const float* __restrict__ g1, const float* __restrict__ be1,
               const float* __restrict__ m1, const float* __restrict__ v1,
               const float* __restrict__ b2, const float* __restrict__ g2,
               const float* __restrict__ be2, const float* __restrict__ m2,
               const float* __restrict__ v2,
               const float* __restrict__ b3, const float* __restrict__ g3,
               const float* __restrict__ be3, const float* __restrict__ m3,
               const float* __restrict__ v3,
               __half* __restrict__ ws)
{
    extern __shared__ char smem[];
    float* patch = reinterpret_cast<float*>(smem);   // 476 f32
    char* s1 = smem + 1904;                          // 390 x 64 B (conv1 out / h2)

    const int bid = blockIdx.x;
    const int p = bid >> 1, half = bid & 1;
    const int tid = threadIdx.x, lane = tid & 63, wave = tid >> 6;
    const int l15 = lane & 15, g = lane >> 4;
    const int base3 = half * 11;

    const __half* w2h = ws + W2H_OFF;
    const __half* w3h = ws + W3H_OFF;

    // ---- patchify: x rows base3..base3+16 of this patch
    {
        const int b = p / 9, r9 = p - b * 9, hb = r9 / 3, wb = r9 - hb * 3;
        const float* xb = x + (size_t)b * 7056 + (hb * 28 + base3) * 84 + wb * 28;
        if (tid < 476) patch[tid] = xb[(tid / 28) * 84 + (tid % 28)];
    }
    __syncthreads();

    // ---- conv1 pass for ci-half h: writes s1[pix 0..389][ci_local 0..31]
    auto conv1 = [&](int h) {
        const int col = lane & 31;
        const int co = h * 32 + col;
        float wr[9];
        #pragma unroll
        for (int t = 0; t < 9; ++t) wr[t] = w1[co * 9 + t];
        const float sc = g1[co] * rsqrtf(v1[co] + EPS);
        const float sh = be1[co] - (m1[co] - b1[co]) * sc;
        for (int pix = wave * 2 + (lane >> 5); pix < 390; pix += 16) {
            const int yy = pix / 26, xx = pix - yy * 26;
            const float* pp = patch + yy * 28 + xx;
            float a = 0.f;
            #pragma unroll
            for (int ky = 0; ky < 3; ++ky)
                #pragma unroll
                for (int kx = 0; kx < 3; ++kx)
                    a = fmaf(pp[ky * 28 + kx], wr[ky * 3 + kx], a);
            const float v = fmaxf(fmaf(a, sc, sh), 0.f);
            *reinterpret_cast<__half*>(s1 + lds64(pix, col * 2)) = __float2half(v);
        }
    };

    // ---- conv2 tiling: M=312 pix (13x24) -> 20 tiles; waves 0-3: 3 tiles, 4-7: 2
    const int npt2 = (wave < 4) ? 3 : 2;
    const int pt0_2 = (wave < 4) ? wave * 3 : 12 + (wave - 4) * 2;
    int rb2[3];
    #pragma unroll
    for (int t = 0; t < 3; ++t) {
        int m = (pt0_2 + t) * 16 + l15;
        if (m > 311) m = 311;
        const int yy = m / 24, xx = m - yy * 24;
        rb2[t] = yy * 26 + xx;
    }
    f32x4 acc2[3][4];
    #pragma unroll
    for (int t = 0; t < 3; ++t)
        #pragma unroll
        for (int ct = 0; ct < 4; ++ct) acc2[t][ct] = (f32x4)0.f;

    auto conv2half = [&](int h) {
        for (int tap = 0; tap < 9; ++tap) {
            const int rowoff = (tap / 3) * 26 + (tap % 3);
            f16x8 wf2[4];
            #pragma unroll
            for (int ct = 0; ct < 4; ++ct)
                wf2[ct] = *reinterpret_cast<const f16x8*>(
                    w2h + (ct * 16 + l15) * 576 + tap * 64 + h * 32 + g * 8);
            for (int t = 0; t < npt2; ++t) {
                const f16x8 af = *reinterpret_cast<const f16x8*>(
                    s1 + lds64(rb2[t] + rowoff, g * 16));
                #pragma unroll
                for (int ct = 0; ct < 4; ++ct)
                    acc2[t][ct] = __builtin_amdgcn_mfma_f32_16x16x32_f16(
                        wf2[ct], af, acc2[t][ct], 0, 0, 0);   // D: row=co, col=pix
            }
        }
    };

    // ---- h2 epilogue for ci-half h (ct = 2h, 2h+1): packed uint2 into s1 region
    auto h2epi = [&](int h) {
        #pragma unroll
        for (int c2 = 0; c2 < 2; ++c2) {
            const int ct = 2 * h + c2;
            const int co0 = ct * 16 + g * 4;
            const float4 gg = *reinterpret_cast<const float4*>(g2 + co0);
            const float4 vv = *reinterpret_cast<const float4*>(v2 + co0);
            const float4 bb = *reinterpret_cast<const float4*>(b2 + co0);
            const float4 mm = *reinterpret_cast<const float4*>(m2 + co0);
            const float4 ee = *reinterpret_cast<const float4*>(be2 + co0);
            float scv[4], shv[4];
            scv[0] = gg.x * rsqrtf(vv.x + EPS); shv[0] = ee.x - (mm.x - bb.x) * scv[0];
            scv[1] = gg.y * rsqrtf(vv.y + EPS); shv[1] = ee.y - (mm.y - bb.y) * scv[1];
            scv[2] = gg.z * rsqrtf(vv.z + EPS); shv[2] = ee.z - (mm.z - bb.z) * scv[2];
            scv[3] = gg.w * rsqrtf(vv.w + EPS); shv[3] = ee.w - (mm.w - bb.w) * scv[3];
            for (int t = 0; t < npt2; ++t) {
                const int m = (pt0_2 + t) * 16 + l15;
                if (m < 312) {
                    float v0 = fmaxf(fmaf(acc2[t][ct][0], scv[0], shv[0]), 0.f);
                    float v1 = fmaxf(fmaf(acc2[t][ct][1], scv[1], shv[1]), 0.f);
                    float v2_ = fmaxf(fmaf(acc2[t][ct][2], scv[2], shv[2]), 0.f);
                    float v3_ = fmaxf(fmaf(acc2[t][ct][3], scv[3], shv[3]), 0.f);
                    uint2 pk = make_uint2(pk2(v0, v1), pk2(v2_, v3_));
                    *reinterpret_cast<uint2*>(s1 + lds64(m, c2 * 32 + g * 8)) = pk;
                }
            }
        }
    };

    // ---- conv3 tiling: M=242 pix (11x22) -> 16 tiles; 2 per wave; N=128 -> 8 co-tiles
    const int pt0_3 = wave * 2;
    int rb3[2];
    #pragma unroll
    for (int t = 0; t < 2; ++t) {
        int m = (pt0_3 + t) * 16 + l15;
        if (m > 241) m = 241;
        const int yy = m / 22, xx = m - yy * 22;
        rb3[t] = yy * 24 + xx;
    }
    f32x4 acc3[2][8];
    #pragma unroll
    for (int t = 0; t < 2; ++t)
        #pragma unroll
        for (int ct = 0; ct < 8; ++ct) acc3[t][ct] = (f32x4)0.f;

    auto conv3half = [&](int h) {
        for (int tap = 0; tap < 9; ++tap) {
            const int rowoff = (tap / 3) * 24 + (tap % 3);
            f16x8 wf3[8];
            #pragma unroll
            for (int ct = 0; ct < 8; ++ct)
                wf3[ct] = *reinterpret_cast<const f16x8*>(
                    w3h + (ct * 16 + l15) * 576 + tap * 64 + h * 32 + g * 8);
            #pragma unroll
            for (int t = 0; t < 2; ++t) {
                const f16x8 af = *reinterpret_cast<const f16x8*>(
                    s1 + lds64(rb3[t] + rowoff, g * 16));
                #pragma unroll
                for (int ct = 0; ct < 8; ++ct)
                    acc3[t][ct] = __builtin_amdgcn_mfma_f32_16x16x32_f16(
                        wf3[ct], af, acc3[t][ct], 0, 0, 0);
            }
        }
    };

    // ---- phase sequence
    conv1(0);      __syncthreads();
    conv2half(0);  __syncthreads();
    conv1(1);      __syncthreads();
    conv2half(1);  __syncthreads();
    h2epi(0);      __syncthreads();
    conv3half(0);  __syncthreads();
    h2epi(1);      __syncthreads();
    conv3half(1);

    // ---- h3 epilogue: packed uint2 to global [pix484][co128]
    {
        __half* slot = ws + H3_OFF + (size_t)p * 61952;
        #pragma unroll
        for (int ct = 0; ct < 8; ++ct) {
            const int co0 = ct * 16 + g * 4;
            const float4 gg = *reinterpret_cast<const float4*>(g3 + co0);
            const float4 vv = *reinterpret_cast<const float4*>(v3 + co0);
            const float4 bb = *reinterpret_cast<const float4*>(b3 + co0);
            const float4 mm = *reinterpret_cast<const float4*>(m3 + co0);
            const float4 ee = *reinterpret_cast<const float4*>(be3 + co0);
            float scv[4], shv[4];
            scv[0] = gg.x * rsqrtf(vv.x + EPS); shv[0] = ee.x - (mm.x - bb.x) * scv[0];
            scv[1] = gg.y * rsqrtf(vv.y + EPS); shv[1] = ee.y - (mm.y - bb.y) * scv[1];
            scv[2] = gg.z * rsqrtf(vv.z + EPS); shv[2] = ee.z - (mm.z - bb.z) * scv[2];
            scv[3] = gg.w * rsqrtf(vv.w + EPS); shv[3] = ee.w - (mm.w - bb.w) * scv[3];
            #pragma unroll
            for (int t = 0; t < 2; ++t) {
                const int m = (pt0_3 + t) * 16 + l15;
                if (m < 242) {
                    float v0 = fmaxf(fmaf(acc3[t][ct][0], scv[0], shv[0]), 0.f);
                    float v1 = fmaxf(fmaf(acc3[t][ct][1], scv[1], shv[1]), 0.f);
                    float v2_ = fmaxf(fmaf(acc3[t][ct][2], scv[2], shv[2]), 0.f);
                    float v3_ = fmaxf(fmaf(acc3[t][ct][3], scv[3], shv[3]), 0.f);
                    uint2 pk = make_uint2(pk2(v0, v1), pk2(v2_, v3_));
                    *reinterpret_cast<uint2*>(slot + (size_t)(242 * half + m) * 128 + co0) = pk;
                }
            }
        }
    }
}

// ---------------- out = bias ----------------
__global__ void k_init(const float* __restrict__ bf, float* __restrict__ out)
{
    const int i = blockIdx.x * 256 + threadIdx.x;
    if (i < 115200) out[i] = bf[i % 100];
}

// ---------------- FC (MFMA): M-block=128 patches, 44 K-chunks, atomics ----------------
__global__ __launch_bounds__(512)
void k_fc(const __half* __restrict__ ws, float* __restrict__ out)
{
    const __half* h3 = ws + H3_OFF;
    const __half* wfh = ws + WFH_OFF;
    const int bid = blockIdx.x;            // 9 mb x 44 kc = 396
    const int mb = bid % 9, kc = bid / 9;
    const int tid = threadIdx.x, lane = tid & 63, wave = tid >> 6;
    const int wm = wave >> 1, wn = wave & 1;
    const int l15 = lane & 15, g = lane >> 4;

    const size_t kbase = (size_t)kc * 1408 + g * 8;
    const __half* Ap[2];
    #pragma unroll
    for (int mt = 0; mt < 2; ++mt) {
        const int patchm = mb * 128 + wm * 32 + mt * 16 + l15;
        Ap[mt] = h3 + (size_t)patchm * 61952 + kbase;
    }
    const __half* Bp[4];
    #pragma unroll
    for (int nt = 0; nt < 4; ++nt) {
        const int orow = wn * 64 + nt * 16 + l15;
        Bp[nt] = wfh + (size_t)orow * 61952 + kbase;
    }

    f32x4 acc[2][4];
    #pragma unroll
    for (int mt = 0; mt < 2; ++mt)
        #pragma unroll
        for (int nt = 0; nt < 4; ++nt) acc[mt][nt] = (f32x4)0.f;

    for (int kk = 0; kk < 44; ++kk) {
        const f16x8 a0 = *reinterpret_cast<const f16x8*>(Ap[0] + kk * 32);
        const f16x8 a1 = *reinterpret_cast<const f16x8*>(Ap[1] + kk * 32);
        f16x8 b[4];
        #pragma unroll
        for (int nt = 0; nt < 4; ++nt)
            b[nt] = *reinterpret_cast<const f16x8*>(Bp[nt] + kk * 32);
        #pragma unroll
        for (int nt = 0; nt < 4; ++nt) {
            acc[0][nt] = __builtin_amdgcn_mfma_f32_16x16x32_f16(a0, b[nt], acc[0][nt], 0, 0, 0);
            acc[1][nt] = __builtin_amdgcn_mfma_f32_16x16x32_f16(a1, b[nt], acc[1][nt], 0, 0, 0);
        }
    }

    #pragma unroll
    for (int mt = 0; mt < 2; ++mt)
        #pragma unroll
        for (int nt = 0; nt < 4; ++nt) {
            const int col = wn * 64 + nt * 16 + l15;
            if (col < 100) {
                #pragma unroll
                for (int r = 0; r < 4; ++r) {
                    const int row = mb * 128 + wm * 32 + mt * 16 + g * 4 + r;
                    atomicAdd(out + (size_t)row * 100 + col, acc[mt][nt][r]);
                }
            }
        }
}

extern "C" void kernel_launch(void* const* d_in, const int* in_sizes, int n_in,
                              void* d_out, int out_size, void* d_ws, size_t ws_size,
                              hipStream_t stream)
{
    const float* x   = (const float*)d_in[0];
    const float* w1  = (const float*)d_in[1];
    const float* b1  = (const float*)d_in[2];
    const float* g1  = (const float*)d_in[3];
    const float* be1 = (const float*)d_in[4];
    const float* m1  = (const float*)d_in[5];
    const float* v1  = (const float*)d_in[6];
    const float* w2  = (const float*)d_in[7];
    const float* b2  = (const float*)d_in[8];
    const float* g2  = (const float*)d_in[9];
    const float* be2 = (const float*)d_in[10];
    const float* m2  = (const float*)d_in[11];
    const float* v2  = (const float*)d_in[12];
    const float* w3  = (const float*)d_in[13];
    const float* b3  = (const float*)d_in[14];
    const float* g3  = (const float*)d_in[15];
    const float* be3 = (const float*)d_in[16];
    const float* m3  = (const float*)d_in[17];
    const float* v3  = (const float*)d_in[18];
    const float* wf  = (const float*)d_in[19];
    const float* bf  = (const float*)d_in[20];

    __half* hws = (__half*)d_ws;     // 158,818,304 B (same as R2)
    float* out = (float*)d_out;

    k_prep<<<24632, 256, 0, stream>>>(w2, w3, wf, hws);
    k_conv123<<<2304, 512, 26864, stream>>>(x, w1, b1, g1, be1, m1, v1,
                                            b2, g2, be2, m2, v2,
                                            b3, g3, be3, m3, v3, hws);
    k_init<<<450, 256, 0, stream>>>(bf, out);
    k_fc<<<396, 512, 0, stream>>>(hws, out);
}

// Round 4
// 1503.690 us; speedup vs baseline: 2.1681x; 2.1681x over previous
//
#include <hip/hip_runtime.h>
#include <hip/hip_fp16.h>

#define EPS 1e-5f

typedef _Float16 f16x8 __attribute__((ext_vector_type(8)));
typedef float f32x4 __attribute__((ext_vector_type(4)));

// ---- ws layout (halfs): 158,818,304 B ----
#define WFH_OFF 0ull
#define W2H_OFF 7929856ull          // 64 x 576
#define W3H_OFF 7966720ull          // 128 x 576
#define H3_OFF  8040448ull          // 1152 x 61952

// ---------------- prep: fp32 -> fp16 weight repacks ----------------
__global__ __launch_bounds__(256)
void k_prep(const float* __restrict__ w2, const float* __restrict__ w3,
            const float* __restrict__ wf, __half* __restrict__ ws)
{
    const int i = blockIdx.x * 256 + threadIdx.x;
    if (i < 6195200) {                       // wfh[o][pix*128+co] = wf[o][co*484+pix]
        const int o = i / 61952, k = i - o * 61952;
        const int co = k & 127, pix = k >> 7;
        ws[WFH_OFF + (size_t)o * 61952 + k] =
            __float2half(wf[(size_t)o * 61952 + co * 484 + pix]);
    } else if (i < 6195200 + 36864) {        // w2h[co][tap*64+ci]
        const int j = i - 6195200;
        const int co = j / 576, k = j - co * 576;
        const int tap = k >> 6, ci = k & 63;
        ws[W2H_OFF + j] = __float2half(w2[co * 576 + ci * 9 + tap]);
    } else if (i < 6195200 + 36864 + 73728) { // w3h[co][tap*64+ci]
        const int j = i - (6195200 + 36864);
        const int co = j / 576, k = j - co * 576;
        const int tap = k >> 6, ci = k & 63;
        ws[W3H_OFF + j] = __float2half(w3[co * 576 + ci * 9 + tap]);
    }
}

// 64-B rows (32 fp16), 16B-granule XOR on (row&3)
__device__ __forceinline__ int lds64(int row, int colByte) {
    return row * 64 + (colByte ^ ((row & 3) << 4));
}
// 128-B rows (64 fp16), 16B-granule XOR on (row&7)
__device__ __forceinline__ int lds128(int row, int colByte) {
    return row * 128 + (colByte ^ ((row & 7) << 4));
}

__device__ __forceinline__ uint32_t pk2(float a, float b) {
    __half2 h = __halves2half2(__float2half(a), __float2half(b));
    return *reinterpret_cast<uint32_t*>(&h);
}

// ---------------- fused conv1 -> conv2 -> conv3, half-patch blocks ----------------
// LDS: patch 476 f32 (1904 B) | conv1-out 390 x 64 B (24960 B) | h2 312 x 128 B (39936 B)
// total 66800 B -> 2 blocks/CU, 16 waves/CU.  Phases strictly sequential: acc2 dead
// before conv3 allocates; conv3 runs as two co-passes (acc 32 VGPRs each).
__global__ __launch_bounds__(512, 4)
void k_conv123(const float* __restrict__ x,
               const float* __restrict__ w1, const float* __restrict__ b1,
               const float* __restrict__ g1, const float* __restrict__ be1,
               const float* __restrict__ m1, const float* __restrict__ v1,
               const float* __restrict__ b2, const float* __restrict__ g2,
               const float* __restrict__ be2, const float* __restrict__ m2,
               const float* __restrict__ v2,
               const float* __restrict__ b3, const float* __restrict__ g3,
               const float* __restrict__ be3, const float* __restrict__ m3,
               const float* __restrict__ v3,
               __half* __restrict__ ws)
{
    extern __shared__ char smem[];
    float* patch = reinterpret_cast<float*>(smem);   // 476 f32
    char* sc1 = smem + 1904;                         // conv1 out, one ci-half
    char* sh2 = smem + 26864;                        // h2, full 64 ch

    const int bid = blockIdx.x;
    const int p = bid >> 1, half = bid & 1;
    const int tid = threadIdx.x, lane = tid & 63, wave = tid >> 6;
    const int l15 = lane & 15, g = lane >> 4;
    const int base3 = half * 11;

    const __half* w2h = ws + W2H_OFF;
    const __half* w3h = ws + W3H_OFF;

    // ---- patchify: x rows base3..base3+16 of this patch
    {
        const int b = p / 9, r9 = p - b * 9, hb = r9 / 3, wb = r9 - hb * 3;
        const float* xb = x + (size_t)b * 7056 + (hb * 28 + base3) * 84 + wb * 28;
        if (tid < 476) patch[tid] = xb[(tid / 28) * 84 + (tid % 28)];
    }
    __syncthreads();

    // ---- conv1 for ci-half h: sc1[pix 0..389][ci_local 0..31]
    auto conv1 = [&](int h) {
        const int col = lane & 31;
        const int co = h * 32 + col;
        float wr[9];
        #pragma unroll
        for (int t = 0; t < 9; ++t) wr[t] = w1[co * 9 + t];
        const float sc = g1[co] * rsqrtf(v1[co] + EPS);
        const float sh = be1[co] - (m1[co] - b1[co]) * sc;
        for (int pix = wave * 2 + (lane >> 5); pix < 390; pix += 16) {
            const int yy = pix / 26, xx = pix - yy * 26;
            const float* pp = patch + yy * 28 + xx;
            float a = 0.f;
            #pragma unroll
            for (int ky = 0; ky < 3; ++ky)
                #pragma unroll
                for (int kx = 0; kx < 3; ++kx)
                    a = fmaf(pp[ky * 28 + kx], wr[ky * 3 + kx], a);
            const float v = fmaxf(fmaf(a, sc, sh), 0.f);
            *reinterpret_cast<__half*>(sc1 + lds64(pix, col * 2)) = __float2half(v);
        }
    };

    // ---- conv2: M=312 (13x24) -> 20 tiles; waves 0-3: 3, waves 4-7: 2
    const int npt2 = (wave < 4) ? 3 : 2;
    const int pt0_2 = (wave < 4) ? wave * 3 : 12 + (wave - 4) * 2;
    int rb2[3];
    #pragma unroll
    for (int t = 0; t < 3; ++t) {
        int m = (pt0_2 + t) * 16 + l15;
        if (m > 311) m = 311;
        const int yy = m / 24, xx = m - yy * 24;
        rb2[t] = yy * 26 + xx;
    }
    f32x4 acc2[3][4];
    #pragma unroll
    for (int t = 0; t < 3; ++t)
        #pragma unroll
        for (int ct = 0; ct < 4; ++ct) acc2[t][ct] = (f32x4)0.f;

    auto conv2half = [&](int h) {
        for (int tap = 0; tap < 9; ++tap) {
            const int rowoff = (tap / 3) * 26 + (tap % 3);
            f16x8 wf2[4];
            #pragma unroll
            for (int ct = 0; ct < 4; ++ct)
                wf2[ct] = *reinterpret_cast<const f16x8*>(
                    w2h + (ct * 16 + l15) * 576 + tap * 64 + h * 32 + g * 8);
            for (int t = 0; t < npt2; ++t) {
                const f16x8 af = *reinterpret_cast<const f16x8*>(
                    sc1 + lds64(rb2[t] + rowoff, g * 16));
                #pragma unroll
                for (int ct = 0; ct < 4; ++ct)
                    acc2[t][ct] = __builtin_amdgcn_mfma_f32_16x16x32_f16(
                        wf2[ct], af, acc2[t][ct], 0, 0, 0);   // D: row=co, col=pix
            }
        }
    };

    // ---- phase 1: conv1/conv2 over both ci-halves
    conv1(0);      __syncthreads();
    conv2half(0);  __syncthreads();
    conv1(1);      __syncthreads();
    conv2half(1);  __syncthreads();

    // ---- h2 epilogue: BN+ReLU -> sh2[pix 312][co 64], packed 8B writes. acc2 dies.
    {
        #pragma unroll
        for (int ct = 0; ct < 4; ++ct) {
            const int co0 = ct * 16 + g * 4;
            const float4 gg = *reinterpret_cast<const float4*>(g2 + co0);
            const float4 vv = *reinterpret_cast<const float4*>(v2 + co0);
            const float4 bb = *reinterpret_cast<const float4*>(b2 + co0);
            const float4 mm = *reinterpret_cast<const float4*>(m2 + co0);
            const float4 ee = *reinterpret_cast<const float4*>(be2 + co0);
            float scv[4], shv[4];
            scv[0] = gg.x * rsqrtf(vv.x + EPS); shv[0] = ee.x - (mm.x - bb.x) * scv[0];
            scv[1] = gg.y * rsqrtf(vv.y + EPS); shv[1] = ee.y - (mm.y - bb.y) * scv[1];
            scv[2] = gg.z * rsqrtf(vv.z + EPS); shv[2] = ee.z - (mm.z - bb.z) * scv[2];
            scv[3] = gg.w * rsqrtf(vv.w + EPS); shv[3] = ee.w - (mm.w - bb.w) * scv[3];
            for (int t = 0; t < npt2; ++t) {
                const int m = (pt0_2 + t) * 16 + l15;
                if (m < 312) {
                    float v0 = fmaxf(fmaf(acc2[t][ct][0], scv[0], shv[0]), 0.f);
                    float v1 = fmaxf(fmaf(acc2[t][ct][1], scv[1], shv[1]), 0.f);
                    float v2_ = fmaxf(fmaf(acc2[t][ct][2], scv[2], shv[2]), 0.f);
                    float v3_ = fmaxf(fmaf(acc2[t][ct][3], scv[3], shv[3]), 0.f);
                    *reinterpret_cast<uint2*>(sh2 + lds128(m, ct * 32 + g * 8)) =
                        make_uint2(pk2(v0, v1), pk2(v2_, v3_));
                }
            }
        }
    }
    __syncthreads();

    // ---- conv3: M=242 (11x22) -> 16 tiles, 2/wave; two co-passes of 64
    const int pt0_3 = wave * 2;
    int rb3[2];
    #pragma unroll
    for (int t = 0; t < 2; ++t) {
        int m = (pt0_3 + t) * 16 + l15;
        if (m > 241) m = 241;
        const int yy = m / 22, xx = m - yy * 22;
        rb3[t] = yy * 24 + xx;
    }
    __half* slot = ws + H3_OFF + (size_t)p * 61952;

    for (int cb = 0; cb < 128; cb += 64) {
        f32x4 acc3[2][4];
        #pragma unroll
        for (int t = 0; t < 2; ++t)
            #pragma unroll
            for (int ct = 0; ct < 4; ++ct) acc3[t][ct] = (f32x4)0.f;

        for (int kk = 0; kk < 18; ++kk) {
            const int tap = kk >> 1;
            const int rowoff = (tap / 3) * 24 + (tap % 3);
            const int cbyte = (kk & 1) * 64 + g * 16;
            f16x8 wf3[4];
            #pragma unroll
            for (int ct = 0; ct < 4; ++ct)
                wf3[ct] = *reinterpret_cast<const f16x8*>(
                    w3h + (cb + ct * 16 + l15) * 576 + tap * 64 + (kk & 1) * 32 + g * 8);
            #pragma unroll
            for (int t = 0; t < 2; ++t) {
                const f16x8 af = *reinterpret_cast<const f16x8*>(
                    sh2 + lds128(rb3[t] + rowoff, cbyte));
                #pragma unroll
                for (int ct = 0; ct < 4; ++ct)
                    acc3[t][ct] = __builtin_amdgcn_mfma_f32_16x16x32_f16(
                        wf3[ct], af, acc3[t][ct], 0, 0, 0);
            }
        }

        // epilogue for this co-pass: packed 8B global writes [pix484][co128]
        #pragma unroll
        for (int ct = 0; ct < 4; ++ct) {
            const int co0 = cb + ct * 16 + g * 4;
            const float4 gg = *reinterpret_cast<const float4*>(g3 + co0);
            const float4 vv = *reinterpret_cast<const float4*>(v3 + co0);
            const float4 bb = *reinterpret_cast<const float4*>(b3 + co0);
            const float4 mm = *reinterpret_cast<const float4*>(m3 + co0);
            const float4 ee = *reinterpret_cast<const float4*>(be3 + co0);
            float scv[4], shv[4];
            scv[0] = gg.x * rsqrtf(vv.x + EPS); shv[0] = ee.x - (mm.x - bb.x) * scv[0];
            scv[1] = gg.y * rsqrtf(vv.y + EPS); shv[1] = ee.y - (mm.y - bb.y) * scv[1];
            scv[2] = gg.z * rsqrtf(vv.z + EPS); shv[2] = ee.z - (mm.z - bb.z) * scv[2];
            scv[3] = gg.w * rsqrtf(vv.w + EPS); shv[3] = ee.w - (mm.w - bb.w) * scv[3];
            #pragma unroll
            for (int t = 0; t < 2; ++t) {
                const int m = (pt0_3 + t) * 16 + l15;
                if (m < 242) {
                    float v0 = fmaxf(fmaf(acc3[t][ct][0], scv[0], shv[0]), 0.f);
                    float v1 = fmaxf(fmaf(acc3[t][ct][1], scv[1], shv[1]), 0.f);
                    float v2_ = fmaxf(fmaf(acc3[t][ct][2], scv[2], shv[2]), 0.f);
                    float v3_ = fmaxf(fmaf(acc3[t][ct][3], scv[3], shv[3]), 0.f);
                    *reinterpret_cast<uint2*>(slot + (size_t)(242 * half + m) * 128 + co0) =
                        make_uint2(pk2(v0, v1), pk2(v2_, v3_));
                }
            }
        }
    }
}

// ---------------- out = bias ----------------
__global__ void k_init(const float* __restrict__ bf, float* __restrict__ out)
{
    const int i = blockIdx.x * 256 + threadIdx.x;
    if (i < 115200) out[i] = bf[i % 100];
}

// ---------------- FC (MFMA): M-block=128 patches, 44 K-chunks, atomics ----------------
__global__ __launch_bounds__(512)
void k_fc(const __half* __restrict__ ws, float* __restrict__ out)
{
    const __half* h3 = ws + H3_OFF;
    const __half* wfh = ws + WFH_OFF;
    const int bid = blockIdx.x;            // 9 mb x 44 kc = 396
    const int mb = bid % 9, kc = bid / 9;
    const int tid = threadIdx.x, lane = tid & 63, wave = tid >> 6;
    const int wm = wave >> 1, wn = wave & 1;
    const int l15 = lane & 15, g = lane >> 4;

    const size_t kbase = (size_t)kc * 1408 + g * 8;
    const __half* Ap[2];
    #pragma unroll
    for (int mt = 0; mt < 2; ++mt) {
        const int patchm = mb * 128 + wm * 32 + mt * 16 + l15;
        Ap[mt] = h3 + (size_t)patchm * 61952 + kbase;
    }
    const __half* Bp[4];
    #pragma unroll
    for (int nt = 0; nt < 4; ++nt) {
        const int orow = wn * 64 + nt * 16 + l15;
        Bp[nt] = wfh + (size_t)orow * 61952 + kbase;
    }

    f32x4 acc[2][4];
    #pragma unroll
    for (int mt = 0; mt < 2; ++mt)
        #pragma unroll
        for (int nt = 0; nt < 4; ++nt) acc[mt][nt] = (f32x4)0.f;

    for (int kk = 0; kk < 44; ++kk) {
        const f16x8 a0 = *reinterpret_cast<const f16x8*>(Ap[0] + kk * 32);
        const f16x8 a1 = *reinterpret_cast<const f16x8*>(Ap[1] + kk * 32);
        f16x8 b[4];
        #pragma unroll
        for (int nt = 0; nt < 4; ++nt)
            b[nt] = *reinterpret_cast<const f16x8*>(Bp[nt] + kk * 32);
        #pragma unroll
        for (int nt = 0; nt < 4; ++nt) {
            acc[0][nt] = __builtin_amdgcn_mfma_f32_16x16x32_f16(a0, b[nt], acc[0][nt], 0, 0, 0);
            acc[1][nt] = __builtin_amdgcn_mfma_f32_16x16x32_f16(a1, b[nt], acc[1][nt], 0, 0, 0);
        }
    }

    #pragma unroll
    for (int mt = 0; mt < 2; ++mt)
        #pragma unroll
        for (int nt = 0; nt < 4; ++nt) {
            const int col = wn * 64 + nt * 16 + l15;
            if (col < 100) {
                #pragma unroll
                for (int r = 0; r < 4; ++r) {
                    const int row = mb * 128 + wm * 32 + mt * 16 + g * 4 + r;
                    atomicAdd(out + (size_t)row * 100 + col, acc[mt][nt][r]);
                }
            }
        }
}

extern "C" void kernel_launch(void* const* d_in, const int* in_sizes, int n_in,
                              void* d_out, int out_size, void* d_ws, size_t ws_size,
                              hipStream_t stream)
{
    const float* x   = (const float*)d_in[0];
    const float* w1  = (const float*)d_in[1];
    const float* b1  = (const float*)d_in[2];
    const float* g1  = (const float*)d_in[3];
    const float* be1 = (const float*)d_in[4];
    const float* m1  = (const float*)d_in[5];
    const float* v1  = (const float*)d_in[6];
    const float* w2  = (const float*)d_in[7];
    const float* b2  = (const float*)d_in[8];
    const float* g2  = (const float*)d_in[9];
    const float* be2 = (const float*)d_in[10];
    const float* m2  = (const float*)d_in[11];
    const float* v2  = (const float*)d_in[12];
    const float* w3  = (const float*)d_in[13];
    const float* b3  = (const float*)d_in[14];
    const float* g3  = (const float*)d_in[15];
    const float* be3 = (const float*)d_in[16];
    const float* m3  = (const float*)d_in[17];
    const float* v3  = (const float*)d_in[18];
    const float* wf  = (const float*)d_in[19];
    const float* bf  = (const float*)d_in[20];

    __half* hws = (__half*)d_ws;     // 158,818,304 B
    float* out = (float*)d_out;

    hipFuncSetAttribute(reinterpret_cast<const void*>(k_conv123),
                        hipFuncAttributeMaxDynamicSharedMemorySize, 66800);

    k_prep<<<24632, 256, 0, stream>>>(w2, w3, wf, hws);
    k_conv123<<<2304, 512, 66800, stream>>>(x, w1, b1, g1, be1, m1, v1,
                                            b2, g2, be2, m2, v2,
                                            b3, g3, be3, m3, v3, hws);
    k_init<<<450, 256, 0, stream>>>(bf, out);
    k_fc<<<396, 512, 0, stream>>>(hws, out);
}

// Round 5
// 656.991 us; speedup vs baseline: 4.9623x; 2.2888x over previous
//
#include <hip/hip_runtime.h>
#include <hip/hip_fp16.h>

#define EPS 1e-5f

typedef _Float16 f16x8 __attribute__((ext_vector_type(8)));
typedef float f32x4 __attribute__((ext_vector_type(4)));

// ---- ws layout (halfs): 158,818,304 B ----
#define WFH_OFF 0ull
#define W2H_OFF 7929856ull          // 64 x 576
#define W3H_OFF 7966720ull          // 128 x 576
#define H3_OFF  8040448ull          // 1152 x 61952

// ---------------- prep: fp32 -> fp16 weight repacks ----------------
__global__ __launch_bounds__(256)
void k_prep(const float* __restrict__ w2, const float* __restrict__ w3,
            const float* __restrict__ wf, __half* __restrict__ ws)
{
    const int i = blockIdx.x * 256 + threadIdx.x;
    if (i < 6195200) {                       // wfh[o][pix*128+co] = wf[o][co*484+pix]
        const int o = i / 61952, k = i - o * 61952;
        const int co = k & 127, pix = k >> 7;
        ws[WFH_OFF + (size_t)o * 61952 + k] =
            __float2half(wf[(size_t)o * 61952 + co * 484 + pix]);
    } else if (i < 6195200 + 36864) {        // w2h[co][tap*64+ci]
        const int j = i - 6195200;
        const int co = j / 576, k = j - co * 576;
        const int tap = k >> 6, ci = k & 63;
        ws[W2H_OFF + j] = __float2half(w2[co * 576 + ci * 9 + tap]);
    } else if (i < 6195200 + 36864 + 73728) { // w3h[co][tap*64+ci]
        const int j = i - (6195200 + 36864);
        const int co = j / 576, k = j - co * 576;
        const int tap = k >> 6, ci = k & 63;
        ws[W3H_OFF + j] = __float2half(w3[co * 576 + ci * 9 + tap]);
    }
}

// 64-B rows (32 fp16), 16B-granule XOR on (row&3)
__device__ __forceinline__ int lds64(int row, int colByte) {
    return row * 64 + (colByte ^ ((row & 3) << 4));
}
// 128-B rows (64 fp16), 16B-granule XOR on (row&7)
__device__ __forceinline__ int lds128(int row, int colByte) {
    return row * 128 + (colByte ^ ((row & 7) << 4));
}

__device__ __forceinline__ uint32_t pk2(float a, float b) {
    __half2 h = __halves2half2(__float2half(a), __float2half(b));
    return *reinterpret_cast<uint32_t*>(&h);
}

// ---------------- fused conv1 -> conv2 -> conv3, half-patch blocks ----------------
// LDS: patch 476 f32 (1904 B) | conv1-out 390 x 64 B (24960 B) | h2 312 x 128 B (39936 B)
// = 66800 B -> 2 blocks/CU, 16 waves/CU.
// ALL register-array loops have compile-time bounds (rule #20: runtime-trip loops
// over acc[]/rb[] put them in scratch -> 4.7 GB HBM traffic in R3/R4).
__global__ __launch_bounds__(512, 4)
void k_conv123(const float* __restrict__ x,
               const float* __restrict__ w1, const float* __restrict__ b1,
               const float* __restrict__ g1, const float* __restrict__ be1,
               const float* __restrict__ m1, const float* __restrict__ v1,
               const float* __restrict__ b2, const float* __restrict__ g2,
               const float* __restrict__ be2, const float* __restrict__ m2,
               const float* __restrict__ v2,
               const float* __restrict__ b3, const float* __restrict__ g3,
               const float* __restrict__ be3, const float* __restrict__ m3,
               const float* __restrict__ v3,
               __half* __restrict__ ws)
{
    extern __shared__ char smem[];
    float* patch = reinterpret_cast<float*>(smem);   // 476 f32
    char* sc1 = smem + 1904;                         // conv1 out, one ci-half
    char* sh2 = smem + 26864;                        // h2, full 64 ch

    const int bid = blockIdx.x;
    const int p = bid >> 1, half = bid & 1;
    const int tid = threadIdx.x, lane = tid & 63, wave = tid >> 6;
    const int l15 = lane & 15, g = lane >> 4;
    const int base3 = half * 11;

    const __half* w2h = ws + W2H_OFF;
    const __half* w3h = ws + W3H_OFF;

    // ---- patchify: x rows base3..base3+16 of this patch
    {
        const int b = p / 9, r9 = p - b * 9, hb = r9 / 3, wb = r9 - hb * 3;
        const float* xb = x + (size_t)b * 7056 + (hb * 28 + base3) * 84 + wb * 28;
        if (tid < 476) patch[tid] = xb[(tid / 28) * 84 + (tid % 28)];
    }
    __syncthreads();

    // ---- conv1 for ci-half h: sc1[pix 0..389][ci_local 0..31]
    auto conv1 = [&](int h) {
        const int col = lane & 31;
        const int co = h * 32 + col;
        float wr[9];
        #pragma unroll
        for (int t = 0; t < 9; ++t) wr[t] = w1[co * 9 + t];
        const float sc = g1[co] * rsqrtf(v1[co] + EPS);
        const float sh = be1[co] - (m1[co] - b1[co]) * sc;
        for (int pix = wave * 2 + (lane >> 5); pix < 390; pix += 16) {
            const int yy = pix / 26, xx = pix - yy * 26;
            const float* pp = patch + yy * 28 + xx;
            float a = 0.f;
            #pragma unroll
            for (int ky = 0; ky < 3; ++ky)
                #pragma unroll
                for (int kx = 0; kx < 3; ++kx)
                    a = fmaf(pp[ky * 28 + kx], wr[ky * 3 + kx], a);
            const float v = fmaxf(fmaf(a, sc, sh), 0.f);
            *reinterpret_cast<__half*>(sc1 + lds64(pix, col * 2)) = __float2half(v);
        }
    };

    // ---- conv2: M=312 (13x24) -> 20 tiles; waves 0-3: 3 tiles, 4-7: 2 (slot 2 idle)
    const int npt2 = (wave < 4) ? 3 : 2;
    const int pt0_2 = (wave < 4) ? wave * 3 : 12 + (wave - 4) * 2;
    int rb2[3];
    #pragma unroll
    for (int t = 0; t < 3; ++t) {
        int m = (pt0_2 + t) * 16 + l15;
        if (m > 311) m = 311;
        const int yy = m / 24, xx = m - yy * 24;
        rb2[t] = yy * 26 + xx;
    }
    f32x4 acc2[3][4];
    #pragma unroll
    for (int t = 0; t < 3; ++t)
        #pragma unroll
        for (int ct = 0; ct < 4; ++ct) acc2[t][ct] = (f32x4)0.f;

    auto conv2half = [&](int h) {
        for (int tap = 0; tap < 9; ++tap) {
            const int rowoff = (tap / 3) * 26 + (tap % 3);
            f16x8 wf2[4];
            #pragma unroll
            for (int ct = 0; ct < 4; ++ct)
                wf2[ct] = *reinterpret_cast<const f16x8*>(
                    w2h + (ct * 16 + l15) * 576 + tap * 64 + h * 32 + g * 8);
            #pragma unroll
            for (int t = 0; t < 3; ++t) {           // STATIC bound; uniform guard
                if (t < npt2) {
                    const f16x8 af = *reinterpret_cast<const f16x8*>(
                        sc1 + lds64(rb2[t] + rowoff, g * 16));
                    #pragma unroll
                    for (int ct = 0; ct < 4; ++ct)
                        acc2[t][ct] = __builtin_amdgcn_mfma_f32_16x16x32_f16(
                            wf2[ct], af, acc2[t][ct], 0, 0, 0);   // D: row=co, col=pix
                }
            }
        }
    };

    // ---- phase 1: conv1/conv2 over both ci-halves
    conv1(0);      __syncthreads();
    conv2half(0);  __syncthreads();
    conv1(1);      __syncthreads();
    conv2half(1);  __syncthreads();

    // ---- h2 epilogue: BN+ReLU -> sh2[pix 312][co 64], packed 8B writes. acc2 dies.
    {
        #pragma unroll
        for (int ct = 0; ct < 4; ++ct) {
            const int co0 = ct * 16 + g * 4;
            const float4 gg = *reinterpret_cast<const float4*>(g2 + co0);
            const float4 vv = *reinterpret_cast<const float4*>(v2 + co0);
            const float4 bb = *reinterpret_cast<const float4*>(b2 + co0);
            const float4 mm = *reinterpret_cast<const float4*>(m2 + co0);
            const float4 ee = *reinterpret_cast<const float4*>(be2 + co0);
            float scv[4], shv[4];
            scv[0] = gg.x * rsqrtf(vv.x + EPS); shv[0] = ee.x - (mm.x - bb.x) * scv[0];
            scv[1] = gg.y * rsqrtf(vv.y + EPS); shv[1] = ee.y - (mm.y - bb.y) * scv[1];
            scv[2] = gg.z * rsqrtf(vv.z + EPS); shv[2] = ee.z - (mm.z - bb.z) * scv[2];
            scv[3] = gg.w * rsqrtf(vv.w + EPS); shv[3] = ee.w - (mm.w - bb.w) * scv[3];
            #pragma unroll
            for (int t = 0; t < 3; ++t) {           // STATIC bound; uniform guard
                const int m = (pt0_2 + t) * 16 + l15;
                if (t < npt2 && m < 312) {
                    float v0 = fmaxf(fmaf(acc2[t][ct][0], scv[0], shv[0]), 0.f);
                    float v1 = fmaxf(fmaf(acc2[t][ct][1], scv[1], shv[1]), 0.f);
                    float v2_ = fmaxf(fmaf(acc2[t][ct][2], scv[2], shv[2]), 0.f);
                    float v3_ = fmaxf(fmaf(acc2[t][ct][3], scv[3], shv[3]), 0.f);
                    *reinterpret_cast<uint2*>(sh2 + lds128(m, ct * 32 + g * 8)) =
                        make_uint2(pk2(v0, v1), pk2(v2_, v3_));
                }
            }
        }
    }
    __syncthreads();

    // ---- conv3: M=242 (11x22) -> 16 tiles, 2/wave (static); two co-passes of 64
    const int pt0_3 = wave * 2;
    int rb3[2];
    #pragma unroll
    for (int t = 0; t < 2; ++t) {
        int m = (pt0_3 + t) * 16 + l15;
        if (m > 241) m = 241;
        const int yy = m / 22, xx = m - yy * 22;
        rb3[t] = yy * 24 + xx;
    }
    __half* slot = ws + H3_OFF + (size_t)p * 61952;

    #pragma unroll
    for (int cp = 0; cp < 2; ++cp) {
        const int cb = cp * 64;
        f32x4 acc3[2][4];
        #pragma unroll
        for (int t = 0; t < 2; ++t)
            #pragma unroll
            for (int ct = 0; ct < 4; ++ct) acc3[t][ct] = (f32x4)0.f;

        for (int kk = 0; kk < 18; ++kk) {
            const int tap = kk >> 1;
            const int rowoff = (tap / 3) * 24 + (tap % 3);
            const int cbyte = (kk & 1) * 64 + g * 16;
            f16x8 wf3[4];
            #pragma unroll
            for (int ct = 0; ct < 4; ++ct)
                wf3[ct] = *reinterpret_cast<const f16x8*>(
                    w3h + (cb + ct * 16 + l15) * 576 + tap * 64 + (kk & 1) * 32 + g * 8);
            #pragma unroll
            for (int t = 0; t < 2; ++t) {
                const f16x8 af = *reinterpret_cast<const f16x8*>(
                    sh2 + lds128(rb3[t] + rowoff, cbyte));
                #pragma unroll
                for (int ct = 0; ct < 4; ++ct)
                    acc3[t][ct] = __builtin_amdgcn_mfma_f32_16x16x32_f16(
                        wf3[ct], af, acc3[t][ct], 0, 0, 0);
            }
        }

        // epilogue for this co-pass: packed 8B global writes [pix484][co128]
        #pragma unroll
        for (int ct = 0; ct < 4; ++ct) {
            const int co0 = cb + ct * 16 + g * 4;
            const float4 gg = *reinterpret_cast<const float4*>(g3 + co0);
            const float4 vv = *reinterpret_cast<const float4*>(v3 + co0);
            const float4 bb = *reinterpret_cast<const float4*>(b3 + co0);
            const float4 mm = *reinterpret_cast<const float4*>(m3 + co0);
            const float4 ee = *reinterpret_cast<const float4*>(be3 + co0);
            float scv[4], shv[4];
            scv[0] = gg.x * rsqrtf(vv.x + EPS); shv[0] = ee.x - (mm.x - bb.x) * scv[0];
            scv[1] = gg.y * rsqrtf(vv.y + EPS); shv[1] = ee.y - (mm.y - bb.y) * scv[1];
            scv[2] = gg.z * rsqrtf(vv.z + EPS); shv[2] = ee.z - (mm.z - bb.z) * scv[2];
            scv[3] = gg.w * rsqrtf(vv.w + EPS); shv[3] = ee.w - (mm.w - bb.w) * scv[3];
            #pragma unroll
            for (int t = 0; t < 2; ++t) {
                const int m = (pt0_3 + t) * 16 + l15;
                if (m < 242) {
                    float v0 = fmaxf(fmaf(acc3[t][ct][0], scv[0], shv[0]), 0.f);
                    float v1 = fmaxf(fmaf(acc3[t][ct][1], scv[1], shv[1]), 0.f);
                    float v2_ = fmaxf(fmaf(acc3[t][ct][2], scv[2], shv[2]), 0.f);
                    float v3_ = fmaxf(fmaf(acc3[t][ct][3], scv[3], shv[3]), 0.f);
                    *reinterpret_cast<uint2*>(slot + (size_t)(242 * half + m) * 128 + co0) =
                        make_uint2(pk2(v0, v1), pk2(v2_, v3_));
                }
            }
        }
    }
}

// ---------------- out = bias ----------------
__global__ void k_init(const float* __restrict__ bf, float* __restrict__ out)
{
    const int i = blockIdx.x * 256 + threadIdx.x;
    if (i < 115200) out[i] = bf[i % 100];
}

// ---------------- FC (MFMA): M-block=128 patches, 44 K-chunks, atomics ----------------
__global__ __launch_bounds__(512)
void k_fc(const __half* __restrict__ ws, float* __restrict__ out)
{
    const __half* h3 = ws + H3_OFF;
    const __half* wfh = ws + WFH_OFF;
    const int bid = blockIdx.x;            // 9 mb x 44 kc = 396
    const int mb = bid % 9, kc = bid / 9;
    const int tid = threadIdx.x, lane = tid & 63, wave = tid >> 6;
    const int wm = wave >> 1, wn = wave & 1;
    const int l15 = lane & 15, g = lane >> 4;

    const size_t kbase = (size_t)kc * 1408 + g * 8;
    const __half* Ap[2];
    #pragma unroll
    for (int mt = 0; mt < 2; ++mt) {
        const int patchm = mb * 128 + wm * 32 + mt * 16 + l15;
        Ap[mt] = h3 + (size_t)patchm * 61952 + kbase;
    }
    const __half* Bp[4];
    #pragma unroll
    for (int nt = 0; nt < 4; ++nt) {
        const int orow = wn * 64 + nt * 16 + l15;
        Bp[nt] = wfh + (size_t)orow * 61952 + kbase;
    }

    f32x4 acc[2][4];
    #pragma unroll
    for (int mt = 0; mt < 2; ++mt)
        #pragma unroll
        for (int nt = 0; nt < 4; ++nt) acc[mt][nt] = (f32x4)0.f;

    for (int kk = 0; kk < 44; ++kk) {
        const f16x8 a0 = *reinterpret_cast<const f16x8*>(Ap[0] + kk * 32);
        const f16x8 a1 = *reinterpret_cast<const f16x8*>(Ap[1] + kk * 32);
        f16x8 b[4];
        #pragma unroll
        for (int nt = 0; nt < 4; ++nt)
            b[nt] = *reinterpret_cast<const f16x8*>(Bp[nt] + kk * 32);
        #pragma unroll
        for (int nt = 0; nt < 4; ++nt) {
            acc[0][nt] = __builtin_amdgcn_mfma_f32_16x16x32_f16(a0, b[nt], acc[0][nt], 0, 0, 0);
            acc[1][nt] = __builtin_amdgcn_mfma_f32_16x16x32_f16(a1, b[nt], acc[1][nt], 0, 0, 0);
        }
    }

    #pragma unroll
    for (int mt = 0; mt < 2; ++mt)
        #pragma unroll
        for (int nt = 0; nt < 4; ++nt) {
            const int col = wn * 64 + nt * 16 + l15;
            if (col < 100) {
                #pragma unroll
                for (int r = 0; r < 4; ++r) {
                    const int row = mb * 128 + wm * 32 + mt * 16 + g * 4 + r;
                    atomicAdd(out + (size_t)row * 100 + col, acc[mt][nt][r]);
                }
            }
        }
}

extern "C" void kernel_launch(void* const* d_in, const int* in_sizes, int n_in,
                              void* d_out, int out_size, void* d_ws, size_t ws_size,
                              hipStream_t stream)
{
    const float* x   = (const float*)d_in[0];
    const float* w1  = (const float*)d_in[1];
    const float* b1  = (const float*)d_in[2];
    const float* g1  = (const float*)d_in[3];
    const float* be1 = (const float*)d_in[4];
    const float* m1  = (const float*)d_in[5];
    const float* v1  = (const float*)d_in[6];
    const float* w2  = (const float*)d_in[7];
    const float* b2  = (const float*)d_in[8];
    const float* g2  = (const float*)d_in[9];
    const float* be2 = (const float*)d_in[10];
    const float* m2  = (const float*)d_in[11];
    const float* v2  = (const float*)d_in[12];
    const float* w3  = (const float*)d_in[13];
    const float* b3  = (const float*)d_in[14];
    const float* g3  = (const float*)d_in[15];
    const float* be3 = (const float*)d_in[16];
    const float* m3  = (const float*)d_in[17];
    const float* v3  = (const float*)d_in[18];
    const float* wf  = (const float*)d_in[19];
    const float* bf  = (const float*)d_in[20];

    __half* hws = (__half*)d_ws;     // 158,818,304 B
    float* out = (float*)d_out;

    hipFuncSetAttribute(reinterpret_cast<const void*>(k_conv123),
                        hipFuncAttributeMaxDynamicSharedMemorySize, 66800);

    k_prep<<<24632, 256, 0, stream>>>(w2, w3, wf, hws);
    k_conv123<<<2304, 512, 66800, stream>>>(x, w1, b1, g1, be1, m1, v1,
                                            b2, g2, be2, m2, v2,
                                            b3, g3, be3, m3, v3, hws);
    k_init<<<450, 256, 0, stream>>>(bf, out);
    k_fc<<<396, 512, 0, stream>>>(hws, out);
}

// Round 6
// 629.814 us; speedup vs baseline: 5.1764x; 1.0432x over previous
//
#include <hip/hip_runtime.h>
#include <hip/hip_fp16.h>

#define EPS 1e-5f

typedef _Float16 f16x8 __attribute__((ext_vector_type(8)));
typedef float f32x4 __attribute__((ext_vector_type(4)));

// ---- ws layout (halfs): 158,818,304 B ----
// wfh k-order = co*484 + pix  (NATIVE wf order -> prep is a straight cast)
#define WFH_OFF 0ull
#define W2H_OFF 7929856ull          // 64 x 576
#define W3H_OFF 7966720ull          // 128 x 576
#define H3_OFF  8040448ull          // 1152 x 61952, layout [co 128][pix 484]

// ---------------- prep ----------------
__global__ __launch_bounds__(256)
void k_prep(const float* __restrict__ w2, const float* __restrict__ w3,
            const float* __restrict__ wf, __half* __restrict__ ws)
{
    const int i = blockIdx.x * 256 + threadIdx.x;
    if (i < 1548800) {                        // wfh: vectorized linear cast (4/thread)
        const float4 f = *reinterpret_cast<const float4*>(wf + (size_t)i * 4);
        __half2 h0 = __floats2half2_rn(f.x, f.y);
        __half2 h1 = __floats2half2_rn(f.z, f.w);
        *reinterpret_cast<uint2*>(ws + WFH_OFF + (size_t)i * 4) =
            make_uint2(*reinterpret_cast<uint32_t*>(&h0), *reinterpret_cast<uint32_t*>(&h1));
    } else if (i < 1548800 + 36864) {         // w2h[co][tap*64+ci]
        const int j = i - 1548800;
        const int co = j / 576, k = j - co * 576;
        const int tap = k >> 6, ci = k & 63;
        ws[W2H_OFF + j] = __float2half(w2[co * 576 + ci * 9 + tap]);
    } else if (i < 1548800 + 36864 + 73728) { // w3h[co][tap*64+ci]
        const int j = i - (1548800 + 36864);
        const int co = j / 576, k = j - co * 576;
        const int tap = k >> 6, ci = k & 63;
        ws[W3H_OFF + j] = __float2half(w3[co * 576 + ci * 9 + tap]);
    }
}

// 128-B rows (64 fp16), 16B-granule XOR on (row&7): 8 granule positions -> 2-way max
__device__ __forceinline__ int lds128(int row, int colByte) {
    return row * 128 + (colByte ^ ((row & 7) << 4));
}

__device__ __forceinline__ uint32_t pk2(float a, float b) {
    __half2 h = __floats2half2_rn(a, b);
    return *reinterpret_cast<uint32_t*>(&h);
}

// ---------------- fused conv1 -> conv2 -> conv3, half-patch blocks ----------------
// LDS: patch 476 f32 (1904 B) | act region 390 x 128 B (49920 B; sc1, then reused as sh2)
// = 51824 B.  4 barriers.  K-loops unrolled x3 with hoisted weight base pointers.
__global__ __launch_bounds__(512, 4)
void k_conv123(const float* __restrict__ x,
               const float* __restrict__ w1, const float* __restrict__ b1,
               const float* __restrict__ g1, const float* __restrict__ be1,
               const float* __restrict__ m1, const float* __restrict__ v1,
               const float* __restrict__ b2, const float* __restrict__ g2,
               const float* __restrict__ be2, const float* __restrict__ m2,
               const float* __restrict__ v2,
               const float* __restrict__ b3, const float* __restrict__ g3,
               const float* __restrict__ be3, const float* __restrict__ m3,
               const float* __restrict__ v3,
               __half* __restrict__ ws)
{
    extern __shared__ char smem[];
    float* patch = reinterpret_cast<float*>(smem);   // 476 f32
    char* act = smem + 1904;                         // 390 x 128 B (sc1 / sh2 aliased)

    const int bid = blockIdx.x;
    const int p = bid >> 1, half = bid & 1;
    const int tid = threadIdx.x, lane = tid & 63, wave = tid >> 6;
    const int l15 = lane & 15, g = lane >> 4;
    const int base3 = half * 11;

    const __half* w2h = ws + W2H_OFF;
    const __half* w3h = ws + W3H_OFF;

    // ---- patchify: x rows base3..base3+16
    {
        const int b = p / 9, r9 = p - b * 9, hb = r9 / 3, wb = r9 - hb * 3;
        const float* xb = x + (size_t)b * 7056 + (hb * 28 + base3) * 84 + wb * 28;
        if (tid < 476) patch[tid] = xb[(tid / 28) * 84 + (tid % 28)];
    }
    __syncthreads();

    // ---- conv1 (single pass, all 64 ch): act[pix 0..389][ci 64]
    {
        const int co = lane;
        float wr[9];
        #pragma unroll
        for (int t = 0; t < 9; ++t) wr[t] = w1[co * 9 + t];
        const float sc = g1[co] * rsqrtf(v1[co] + EPS);
        const float sh = be1[co] - (m1[co] - b1[co]) * sc;
        for (int pix = wave; pix < 390; pix += 8) {
            const int yy = pix / 26, xx = pix - yy * 26;
            const float* pp = patch + yy * 28 + xx;   // wave-uniform -> LDS broadcast
            float a = 0.f;
            #pragma unroll
            for (int ky = 0; ky < 3; ++ky)
                #pragma unroll
                for (int kx = 0; kx < 3; ++kx)
                    a = fmaf(pp[ky * 28 + kx], wr[ky * 3 + kx], a);
            const float v = fmaxf(fmaf(a, sc, sh), 0.f);
            *reinterpret_cast<__half*>(act + lds128(pix, co * 2)) = __float2half(v);
        }
    }
    __syncthreads();

    // ---- conv2: M=312 (13x24) -> 20 tiles; waves 0-3: 3 tiles, 4-7: 2. Full K=576.
    const int npt2 = (wave < 4) ? 3 : 2;
    const int pt0_2 = (wave < 4) ? wave * 3 : 12 + (wave - 4) * 2;
    int rb2[3];
    #pragma unroll
    for (int t = 0; t < 3; ++t) {
        int m = (pt0_2 + t) * 16 + l15;
        if (m > 311) m = 311;
        const int yy = m / 24, xx = m - yy * 24;
        rb2[t] = yy * 26 + xx;
    }
    f32x4 acc2[3][4];
    #pragma unroll
    for (int t = 0; t < 3; ++t)
        #pragma unroll
        for (int ct = 0; ct < 4; ++ct) acc2[t][ct] = (f32x4)0.f;

    {
        const __half* bp2[4];      // hoisted weight bases -> inner loads are base+imm
        #pragma unroll
        for (int ct = 0; ct < 4; ++ct)
            bp2[ct] = w2h + (ct * 16 + l15) * 576 + g * 8;

        #pragma unroll 3
        for (int kk = 0; kk < 18; ++kk) {     // k-step = (tap = kk>>1, ci-half = kk&1)
            const int tap = kk >> 1;
            const int rowoff = (tap / 3) * 26 + (tap % 3);
            const int cbyte = (kk & 1) * 64 + g * 16;
            f16x8 wf2[4];
            #pragma unroll
            for (int ct = 0; ct < 4; ++ct)
                wf2[ct] = *reinterpret_cast<const f16x8*>(bp2[ct] + kk * 32);
            #pragma unroll
            for (int t = 0; t < 3; ++t) {
                if (t < npt2) {
                    const f16x8 af = *reinterpret_cast<const f16x8*>(
                        act + lds128(rb2[t] + rowoff, cbyte));
                    #pragma unroll
                    for (int ct = 0; ct < 4; ++ct)
                        acc2[t][ct] = __builtin_amdgcn_mfma_f32_16x16x32_f16(
                            wf2[ct], af, acc2[t][ct], 0, 0, 0);   // D: row=co, col=pix
                }
            }
        }
    }
    __syncthreads();   // all conv1 data consumed; act region may be overwritten

    // ---- h2 epilogue: BN+ReLU -> act[pix 0..311][co 64] (aliases sc1). acc2 dies.
    {
        #pragma unroll
        for (int ct = 0; ct < 4; ++ct) {
            const int co0 = ct * 16 + g * 4;
            const float4 gg = *reinterpret_cast<const float4*>(g2 + co0);
            const float4 vv = *reinterpret_cast<const float4*>(v2 + co0);
            const float4 bb = *reinterpret_cast<const float4*>(b2 + co0);
            const float4 mm = *reinterpret_cast<const float4*>(m2 + co0);
            const float4 ee = *reinterpret_cast<const float4*>(be2 + co0);
            float scv[4], shv[4];
            scv[0] = gg.x * rsqrtf(vv.x + EPS); shv[0] = ee.x - (mm.x - bb.x) * scv[0];
            scv[1] = gg.y * rsqrtf(vv.y + EPS); shv[1] = ee.y - (mm.y - bb.y) * scv[1];
            scv[2] = gg.z * rsqrtf(vv.z + EPS); shv[2] = ee.z - (mm.z - bb.z) * scv[2];
            scv[3] = gg.w * rsqrtf(vv.w + EPS); shv[3] = ee.w - (mm.w - bb.w) * scv[3];
            #pragma unroll
            for (int t = 0; t < 3; ++t) {
                const int m = (pt0_2 + t) * 16 + l15;
                if (t < npt2 && m < 312) {
                    float v0 = fmaxf(fmaf(acc2[t][ct][0], scv[0], shv[0]), 0.f);
                    float v1 = fmaxf(fmaf(acc2[t][ct][1], scv[1], shv[1]), 0.f);
                    float v2_ = fmaxf(fmaf(acc2[t][ct][2], scv[2], shv[2]), 0.f);
                    float v3_ = fmaxf(fmaf(acc2[t][ct][3], scv[3], shv[3]), 0.f);
                    *reinterpret_cast<uint2*>(act + lds128(m, ct * 32 + g * 8)) =
                        make_uint2(pk2(v0, v1), pk2(v2_, v3_));
                }
            }
        }
    }
    __syncthreads();

    // ---- conv3: M=242 (11x22) -> 16 tiles, 2/wave; two co-passes of 64
    const int pt0_3 = wave * 2;
    int rb3[2];
    #pragma unroll
    for (int t = 0; t < 2; ++t) {
        int m = (pt0_3 + t) * 16 + l15;
        if (m > 241) m = 241;
        const int yy = m / 22, xx = m - yy * 22;
        rb3[t] = yy * 24 + xx;
    }
    __half* slot = ws + H3_OFF + (size_t)p * 61952;   // [co 128][pix 484]

    #pragma unroll
    for (int cp = 0; cp < 2; ++cp) {
        const int cb = cp * 64;
        f32x4 acc3[2][4];
        #pragma unroll
        for (int t = 0; t < 2; ++t)
            #pragma unroll
            for (int ct = 0; ct < 4; ++ct) acc3[t][ct] = (f32x4)0.f;

        const __half* bp3[4];
        #pragma unroll
        for (int ct = 0; ct < 4; ++ct)
            bp3[ct] = w3h + (cb + ct * 16 + l15) * 576 + g * 8;

        #pragma unroll 3
        for (int kk = 0; kk < 18; ++kk) {
            const int tap = kk >> 1;
            const int rowoff = (tap / 3) * 24 + (tap % 3);
            const int cbyte = (kk & 1) * 64 + g * 16;
            f16x8 wf3[4];
            #pragma unroll
            for (int ct = 0; ct < 4; ++ct)
                wf3[ct] = *reinterpret_cast<const f16x8*>(bp3[ct] + kk * 32);
            #pragma unroll
            for (int t = 0; t < 2; ++t) {
                const f16x8 af = *reinterpret_cast<const f16x8*>(
                    act + lds128(rb3[t] + rowoff, cbyte));
                #pragma unroll
                for (int ct = 0; ct < 4; ++ct)
                    acc3[t][ct] = __builtin_amdgcn_mfma_f32_16x16x32_f16(
                        wf3[ct], af, acc3[t][ct], 0, 0, 0);
            }
        }

        // epilogue: BN+ReLU -> h3[co][pix]; 16-lane 32-B contiguous runs
        #pragma unroll
        for (int ct = 0; ct < 4; ++ct) {
            const int co0 = cb + ct * 16 + g * 4;
            const float4 gg = *reinterpret_cast<const float4*>(g3 + co0);
            const float4 vv = *reinterpret_cast<const float4*>(v3 + co0);
            const float4 bb = *reinterpret_cast<const float4*>(b3 + co0);
            const float4 mm = *reinterpret_cast<const float4*>(m3 + co0);
            const float4 ee = *reinterpret_cast<const float4*>(be3 + co0);
            float scv[4], shv[4];
            scv[0] = gg.x * rsqrtf(vv.x + EPS); shv[0] = ee.x - (mm.x - bb.x) * scv[0];
            scv[1] = gg.y * rsqrtf(vv.y + EPS); shv[1] = ee.y - (mm.y - bb.y) * scv[1];
            scv[2] = gg.z * rsqrtf(vv.z + EPS); shv[2] = ee.z - (mm.z - bb.z) * scv[2];
            scv[3] = gg.w * rsqrtf(vv.w + EPS); shv[3] = ee.w - (mm.w - bb.w) * scv[3];
            #pragma unroll
            for (int t = 0; t < 2; ++t) {
                const int m = (pt0_3 + t) * 16 + l15;
                if (m < 242) {
                    const int pixg = 242 * half + m;
                    slot[(size_t)(co0 + 0) * 484 + pixg] =
                        __float2half(fmaxf(fmaf(acc3[t][ct][0], scv[0], shv[0]), 0.f));
                    slot[(size_t)(co0 + 1) * 484 + pixg] =
                        __float2half(fmaxf(fmaf(acc3[t][ct][1], scv[1], shv[1]), 0.f));
                    slot[(size_t)(co0 + 2) * 484 + pixg] =
                        __float2half(fmaxf(fmaf(acc3[t][ct][2], scv[2], shv[2]), 0.f));
                    slot[(size_t)(co0 + 3) * 484 + pixg] =
                        __float2half(fmaxf(fmaf(acc3[t][ct][3], scv[3], shv[3]), 0.f));
                }
            }
        }
    }
}

// ---------------- out = bias ----------------
__global__ void k_init(const float* __restrict__ bf, float* __restrict__ out)
{
    const int i = blockIdx.x * 256 + threadIdx.x;
    if (i < 115200) out[i] = bf[i % 100];
}

// ---------------- FC (MFMA): M-block=128 patches, 44 K-chunks, atomics ----------------
__global__ __launch_bounds__(512)
void k_fc(const __half* __restrict__ ws, float* __restrict__ out)
{
    const __half* h3 = ws + H3_OFF;
    const __half* wfh = ws + WFH_OFF;
    const int bid = blockIdx.x;            // 9 mb x 44 kc = 396
    const int mb = bid % 9, kc = bid / 9;
    const int tid = threadIdx.x, lane = tid & 63, wave = tid >> 6;
    const int wm = wave >> 1, wn = wave & 1;
    const int l15 = lane & 15, g = lane >> 4;

    const size_t kbase = (size_t)kc * 1408 + g * 8;
    const __half* Ap[2];
    #pragma unroll
    for (int mt = 0; mt < 2; ++mt) {
        const int patchm = mb * 128 + wm * 32 + mt * 16 + l15;
        Ap[mt] = h3 + (size_t)patchm * 61952 + kbase;
    }
    const __half* Bp[4];
    #pragma unroll
    for (int nt = 0; nt < 4; ++nt) {
        const int orow = wn * 64 + nt * 16 + l15;
        Bp[nt] = wfh + (size_t)orow * 61952 + kbase;
    }

    f32x4 acc[2][4];
    #pragma unroll
    for (int mt = 0; mt < 2; ++mt)
        #pragma unroll
        for (int nt = 0; nt < 4; ++nt) acc[mt][nt] = (f32x4)0.f;

    #pragma unroll 4
    for (int kk = 0; kk < 44; ++kk) {
        const f16x8 a0 = *reinterpret_cast<const f16x8*>(Ap[0] + kk * 32);
        const f16x8 a1 = *reinterpret_cast<const f16x8*>(Ap[1] + kk * 32);
        f16x8 b[4];
        #pragma unroll
        for (int nt = 0; nt < 4; ++nt)
            b[nt] = *reinterpret_cast<const f16x8*>(Bp[nt] + kk * 32);
        #pragma unroll
        for (int nt = 0; nt < 4; ++nt) {
            acc[0][nt] = __builtin_amdgcn_mfma_f32_16x16x32_f16(a0, b[nt], acc[0][nt], 0, 0, 0);
            acc[1][nt] = __builtin_amdgcn_mfma_f32_16x16x32_f16(a1, b[nt], acc[1][nt], 0, 0, 0);
        }
    }

    #pragma unroll
    for (int mt = 0; mt < 2; ++mt)
        #pragma unroll
        for (int nt = 0; nt < 4; ++nt) {
            const int col = wn * 64 + nt * 16 + l15;
            if (col < 100) {
                #pragma unroll
                for (int r = 0; r < 4; ++r) {
                    const int row = mb * 128 + wm * 32 + mt * 16 + g * 4 + r;
                    atomicAdd(out + (size_t)row * 100 + col, acc[mt][nt][r]);
                }
            }
        }
}

extern "C" void kernel_launch(void* const* d_in, const int* in_sizes, int n_in,
                              void* d_out, int out_size, void* d_ws, size_t ws_size,
                              hipStream_t stream)
{
    const float* x   = (const float*)d_in[0];
    const float* w1  = (const float*)d_in[1];
    const float* b1  = (const float*)d_in[2];
    const float* g1  = (const float*)d_in[3];
    const float* be1 = (const float*)d_in[4];
    const float* m1  = (const float*)d_in[5];
    const float* v1  = (const float*)d_in[6];
    const float* w2  = (const float*)d_in[7];
    const float* b2  = (const float*)d_in[8];
    const float* g2  = (const float*)d_in[9];
    const float* be2 = (const float*)d_in[10];
    const float* m2  = (const float*)d_in[11];
    const float* v2  = (const float*)d_in[12];
    const float* w3  = (const float*)d_in[13];
    const float* b3  = (const float*)d_in[14];
    const float* g3  = (const float*)d_in[15];
    const float* be3 = (const float*)d_in[16];
    const float* m3  = (const float*)d_in[17];
    const float* v3  = (const float*)d_in[18];
    const float* wf  = (const float*)d_in[19];
    const float* bf  = (const float*)d_in[20];

    __half* hws = (__half*)d_ws;     // 158,818,304 B
    float* out = (float*)d_out;

    k_prep<<<6483, 256, 0, stream>>>(w2, w3, wf, hws);
    k_conv123<<<2304, 512, 51824, stream>>>(x, w1, b1, g1, be1, m1, v1,
                                            b2, g2, be2, m2, v2,
                                            b3, g3, be3, m3, v3, hws);
    k_init<<<450, 256, 0, stream>>>(bf, out);
    k_fc<<<396, 512, 0, stream>>>(hws, out);
}

// Round 7
// 362.574 us; speedup vs baseline: 8.9917x; 1.7371x over previous
//
#include <hip/hip_runtime.h>
#include <hip/hip_fp16.h>

#define EPS 1e-5f

typedef _Float16 f16x8 __attribute__((ext_vector_type(8)));
typedef float f32x4 __attribute__((ext_vector_type(4)));

// ---- ws layout (halfs): 155,348,992 B ----
// wfh: native wf k-order (co*484+pix), straight fp16 cast
// w2p: [kk 18][co 64][kl 32]    (kk-step k = kk*32+kl; tap=kk>>1, ci=(kk&1)*32+kl)
// w3p: [cp 2][kk 18][co 64][kl 32]
#define WFH_OFF 0ull
#define W2P_OFF 6195200ull
#define W3P_OFF 6232064ull
#define H3_OFF  6305792ull          // 1152 x 61952, per patch [co 128][pix 484]

// ---------------- prep ----------------
__global__ __launch_bounds__(256)
void k_prep(const float* __restrict__ w2, const float* __restrict__ w3,
            const float* __restrict__ wf, __half* __restrict__ ws)
{
    const int i = blockIdx.x * 256 + threadIdx.x;
    if (i < 1548800) {                        // wfh: vectorized linear cast (4/thread)
        const float4 f = *reinterpret_cast<const float4*>(wf + (size_t)i * 4);
        __half2 h0 = __floats2half2_rn(f.x, f.y);
        __half2 h1 = __floats2half2_rn(f.z, f.w);
        *reinterpret_cast<uint2*>(ws + WFH_OFF + (size_t)i * 4) =
            make_uint2(*reinterpret_cast<uint32_t*>(&h0), *reinterpret_cast<uint32_t*>(&h1));
    } else if (i < 1548800 + 36864) {         // w2p[kk][co][kl]
        const int j = i - 1548800;
        const int kk = j >> 11, rem = j & 2047;
        const int co = rem >> 5, kl = rem & 31;
        const int tap = kk >> 1, ci = (kk & 1) * 32 + kl;
        ws[W2P_OFF + j] = __float2half(w2[co * 576 + ci * 9 + tap]);
    } else if (i < 1548800 + 36864 + 73728) { // w3p[cp][kk][co][kl]
        const int j = i - (1548800 + 36864);
        const int cp = j / 36864, r = j % 36864;
        const int kk = r >> 11, rem = r & 2047;
        const int col = rem >> 5, kl = rem & 31;
        const int co = cp * 64 + col;
        const int tap = kk >> 1, ci = (kk & 1) * 32 + kl;
        ws[W3P_OFF + j] = __float2half(w3[co * 576 + ci * 9 + tap]);
    }
}

// act: 128-B rows (64 fp16), 16B-granule XOR on (row&7)
__device__ __forceinline__ int lds128(int row, int colByte) {
    return row * 128 + (colByte ^ ((row & 7) << 4));
}

__device__ __forceinline__ uint32_t pk2(float a, float b) {
    __half2 h = __floats2half2_rn(a, b);
    return *reinterpret_cast<uint32_t*>(&h);
}

// ---------------- fused conv1 -> conv2 -> conv3, FULL-patch blocks ----------------
// LDS: act 676x128 (86528) | wbuf 73728 (w2s / w3s-cp0 / w3s-cp1) | patch 784 f32 (3136)
// = 163392 B (1 block/CU). K-loops read ONLY LDS: weight frags are contiguous 1024 B
// per wave (conflict-free), act frags swizzled. Zero global loads in the hot loops.
__global__ __launch_bounds__(512, 2)
void k_conv123(const float* __restrict__ x,
               const float* __restrict__ w1, const float* __restrict__ b1,
               const float* __restrict__ g1, const float* __restrict__ be1,
               const float* __restrict__ m1, const float* __restrict__ v1,
               const float* __restrict__ b2, const float* __restrict__ g2,
               const float* __restrict__ be2, const float* __restrict__ m2,
               const float* __restrict__ v2,
               const float* __restrict__ b3, const float* __restrict__ g3,
               const float* __restrict__ be3, const float* __restrict__ m3,
               const float* __restrict__ v3,
               __half* __restrict__ ws)
{
    extern __shared__ char smem[];
    char* act = smem;                                   // 86528 B
    char* wbuf = smem + 86528;                          // 73728 B
    float* patch = reinterpret_cast<float*>(smem + 160256);  // 784 f32

    const int p = blockIdx.x;
    const int tid = threadIdx.x, lane = tid & 63, wave = tid >> 6;
    const int l15 = lane & 15, g = lane >> 4;

    const __half* w2p = ws + W2P_OFF;
    const __half* w3p = ws + W3P_OFF;

    // ---- weight staging helper: 73728 B linear copy (9 x uint4 per thread)
    auto stage = [&](const __half* src) {
        uint4 v[9];
        #pragma unroll
        for (int u = 0; u < 9; ++u)
            v[u] = *reinterpret_cast<const uint4*>(src + (size_t)(tid + u * 512) * 8);
        #pragma unroll
        for (int u = 0; u < 9; ++u)
            *reinterpret_cast<uint4*>(wbuf + (tid + u * 512) * 16) = v[u];
    };

    // ---- patchify (full 28x28) + stage w2s
    {
        const int b = p / 9, r9 = p - b * 9, hb = r9 / 3, wb = r9 - hb * 3;
        const float* xb = x + (size_t)b * 7056 + hb * 28 * 84 + wb * 28;
        #pragma unroll
        for (int u = 0; u < 2; ++u) {
            const int i = tid + u * 512;
            if (i < 784) patch[i] = xb[(i / 28) * 84 + (i % 28)];
        }
    }
    stage(w2p);          // w2s resident by the barrier
    __syncthreads();

    // ---- conv1 (all 64 ch): act[pix 0..675][ci 64]
    {
        const int co = lane;
        float wr[9];
        #pragma unroll
        for (int t = 0; t < 9; ++t) wr[t] = w1[co * 9 + t];
        const float sc = g1[co] * rsqrtf(v1[co] + EPS);
        const float sh = be1[co] - (m1[co] - b1[co]) * sc;
        for (int pix = wave; pix < 676; pix += 8) {
            const int yy = pix / 26, xx = pix - yy * 26;
            const float* pp = patch + yy * 28 + xx;     // wave-uniform -> broadcast
            float a = 0.f;
            #pragma unroll
            for (int ky = 0; ky < 3; ++ky)
                #pragma unroll
                for (int kx = 0; kx < 3; ++kx)
                    a = fmaf(pp[ky * 28 + kx], wr[ky * 3 + kx], a);
            const float v = fmaxf(fmaf(a, sc, sh), 0.f);
            *reinterpret_cast<__half*>(act + lds128(pix, co * 2)) = __float2half(v);
        }
    }
    __syncthreads();

    // ---- conv2: M=576 (24x24) -> 36 tiles; waves 0-3: 5 tiles, 4-7: 4
    const int npt2 = (wave < 4) ? 5 : 4;
    const int mt0 = (wave < 4) ? wave * 5 : 20 + (wave - 4) * 4;
    int rb2[5];
    #pragma unroll
    for (int t = 0; t < 5; ++t) {
        int mt = mt0 + t; if (mt > 35) mt = 35;
        const int m = mt * 16 + l15;
        const int yy = m / 24, xx = m - yy * 24;
        rb2[t] = yy * 26 + xx;
    }
    f32x4 acc2[5][4];
    #pragma unroll
    for (int t = 0; t < 5; ++t)
        #pragma unroll
        for (int ct = 0; ct < 4; ++ct) acc2[t][ct] = (f32x4)0.f;

    for (int kk = 0; kk < 18; ++kk) {
        const int tap = kk >> 1;
        const int rowoff = (tap / 3) * 26 + (tap % 3);
        const int cbyte = (kk & 1) * 64 + g * 16;
        f16x8 wfr[4];
        #pragma unroll
        for (int ct = 0; ct < 4; ++ct)   // contiguous 1024 B per wave: conflict-free
            wfr[ct] = *reinterpret_cast<const f16x8*>(
                wbuf + kk * 4096 + (ct * 16 + l15) * 64 + g * 16);
        #pragma unroll
        for (int t = 0; t < 5; ++t) {
            if (t < npt2) {
                const f16x8 af = *reinterpret_cast<const f16x8*>(
                    act + lds128(rb2[t] + rowoff, cbyte));
                #pragma unroll
                for (int ct = 0; ct < 4; ++ct)
                    acc2[t][ct] = __builtin_amdgcn_mfma_f32_16x16x32_f16(
                        wfr[ct], af, acc2[t][ct], 0, 0, 0);  // D: row=co, col=pix
            }
        }
    }
    __syncthreads();   // conv2 reads of act & wbuf done

    // ---- stage w3s-cp0 (issue loads first) + h2 epilogue -> act[pix 0..575][co 64]
    {
        uint4 v[9];
        #pragma unroll
        for (int u = 0; u < 9; ++u)
            v[u] = *reinterpret_cast<const uint4*>(w3p + (size_t)(tid + u * 512) * 8);

        #pragma unroll
        for (int ct = 0; ct < 4; ++ct) {
            const int co0 = ct * 16 + g * 4;
            const float4 gg = *reinterpret_cast<const float4*>(g2 + co0);
            const float4 vv = *reinterpret_cast<const float4*>(v2 + co0);
            const float4 bb = *reinterpret_cast<const float4*>(b2 + co0);
            const float4 mm = *reinterpret_cast<const float4*>(m2 + co0);
            const float4 ee = *reinterpret_cast<const float4*>(be2 + co0);
            float scv[4], shv[4];
            scv[0] = gg.x * rsqrtf(vv.x + EPS); shv[0] = ee.x - (mm.x - bb.x) * scv[0];
            scv[1] = gg.y * rsqrtf(vv.y + EPS); shv[1] = ee.y - (mm.y - bb.y) * scv[1];
            scv[2] = gg.z * rsqrtf(vv.z + EPS); shv[2] = ee.z - (mm.z - bb.z) * scv[2];
            scv[3] = gg.w * rsqrtf(vv.w + EPS); shv[3] = ee.w - (mm.w - bb.w) * scv[3];
            #pragma unroll
            for (int t = 0; t < 5; ++t) {
                const int m = (mt0 + t) * 16 + l15;
                if (t < npt2 && m < 576) {
                    float v0 = fmaxf(fmaf(acc2[t][ct][0], scv[0], shv[0]), 0.f);
                    float v1 = fmaxf(fmaf(acc2[t][ct][1], scv[1], shv[1]), 0.f);
                    float v2_ = fmaxf(fmaf(acc2[t][ct][2], scv[2], shv[2]), 0.f);
                    float v3_ = fmaxf(fmaf(acc2[t][ct][3], scv[3], shv[3]), 0.f);
                    *reinterpret_cast<uint2*>(act + lds128(m, ct * 32 + g * 8)) =
                        make_uint2(pk2(v0, v1), pk2(v2_, v3_));
                }
            }
        }
        #pragma unroll
        for (int u = 0; u < 9; ++u)
            *reinterpret_cast<uint4*>(wbuf + (tid + u * 512) * 16) = v[u];
    }
    __syncthreads();

    // ---- conv3: M=484 (22x22) -> 31 tiles; every wave 4 tiles; two co-passes of 64
    int rb3[4];
    #pragma unroll
    for (int t = 0; t < 4; ++t) {
        int m = (wave * 4 + t) * 16 + l15;
        if (m > 483) m = 483;
        const int yy = m / 22, xx = m - yy * 22;
        rb3[t] = yy * 24 + xx;
    }
    __half* slot = ws + H3_OFF + (size_t)p * 61952;   // [co 128][pix 484]

    #pragma unroll
    for (int cp = 0; cp < 2; ++cp) {
        const int cb = cp * 64;
        f32x4 acc3[4][4];
        #pragma unroll
        for (int t = 0; t < 4; ++t)
            #pragma unroll
            for (int ct = 0; ct < 4; ++ct) acc3[t][ct] = (f32x4)0.f;

        for (int kk = 0; kk < 18; ++kk) {
            const int tap = kk >> 1;
            const int rowoff = (tap / 3) * 24 + (tap % 3);
            const int cbyte = (kk & 1) * 64 + g * 16;
            f16x8 wfr[4];
            #pragma unroll
            for (int ct = 0; ct < 4; ++ct)
                wfr[ct] = *reinterpret_cast<const f16x8*>(
                    wbuf + kk * 4096 + (ct * 16 + l15) * 64 + g * 16);
            #pragma unroll
            for (int t = 0; t < 4; ++t) {
                const f16x8 af = *reinterpret_cast<const f16x8*>(
                    act + lds128(rb3[t] + rowoff, cbyte));
                #pragma unroll
                for (int ct = 0; ct < 4; ++ct)
                    acc3[t][ct] = __builtin_amdgcn_mfma_f32_16x16x32_f16(
                        wfr[ct], af, acc3[t][ct], 0, 0, 0);
            }
        }
        __syncthreads();   // cp reads of wbuf done (before cp1 restage)

        // stage cp1 weights (issue loads before epilogue; write after)
        uint4 sv[9];
        if (cp == 0) {
            #pragma unroll
            for (int u = 0; u < 9; ++u)
                sv[u] = *reinterpret_cast<const uint4*>(
                    w3p + 36864 + (size_t)(tid + u * 512) * 8);
        }

        // epilogue: BN+ReLU -> h3[co][pix] (16-lane 32-B runs)
        #pragma unroll
        for (int ct = 0; ct < 4; ++ct) {
            const int co0 = cb + ct * 16 + g * 4;
            const float4 gg = *reinterpret_cast<const float4*>(g3 + co0);
            const float4 vv = *reinterpret_cast<const float4*>(v3 + co0);
            const float4 bb = *reinterpret_cast<const float4*>(b3 + co0);
            const float4 mm = *reinterpret_cast<const float4*>(m3 + co0);
            const float4 ee = *reinterpret_cast<const float4*>(be3 + co0);
            float scv[4], shv[4];
            scv[0] = gg.x * rsqrtf(vv.x + EPS); shv[0] = ee.x - (mm.x - bb.x) * scv[0];
            scv[1] = gg.y * rsqrtf(vv.y + EPS); shv[1] = ee.y - (mm.y - bb.y) * scv[1];
            scv[2] = gg.z * rsqrtf(vv.z + EPS); shv[2] = ee.z - (mm.z - bb.z) * scv[2];
            scv[3] = gg.w * rsqrtf(vv.w + EPS); shv[3] = ee.w - (mm.w - bb.w) * scv[3];
            #pragma unroll
            for (int t = 0; t < 4; ++t) {
                const int m = (wave * 4 + t) * 16 + l15;
                if (m < 484) {
                    slot[(size_t)(co0 + 0) * 484 + m] =
                        __float2half(fmaxf(fmaf(acc3[t][ct][0], scv[0], shv[0]), 0.f));
                    slot[(size_t)(co0 + 1) * 484 + m] =
                        __float2half(fmaxf(fmaf(acc3[t][ct][1], scv[1], shv[1]), 0.f));
                    slot[(size_t)(co0 + 2) * 484 + m] =
                        __float2half(fmaxf(fmaf(acc3[t][ct][2], scv[2], shv[2]), 0.f));
                    slot[(size_t)(co0 + 3) * 484 + m] =
                        __float2half(fmaxf(fmaf(acc3[t][ct][3], scv[3], shv[3]), 0.f));
                }
            }
        }

        if (cp == 0) {
            #pragma unroll
            for (int u = 0; u < 9; ++u)
                *reinterpret_cast<uint4*>(wbuf + (tid + u * 512) * 16) = sv[u];
            __syncthreads();
        }
    }
}

// ---------------- out = bias ----------------
__global__ void k_init(const float* __restrict__ bf, float* __restrict__ out)
{
    const int i = blockIdx.x * 256 + threadIdx.x;
    if (i < 115200) out[i] = bf[i % 100];
}

// ---------------- FC (MFMA): M-block=128 patches, 44 K-chunks, atomics ----------------
__global__ __launch_bounds__(512)
void k_fc(const __half* __restrict__ ws, float* __restrict__ out)
{
    const __half* h3 = ws + H3_OFF;
    const __half* wfh = ws + WFH_OFF;
    const int bid = blockIdx.x;            // 9 mb x 44 kc = 396
    const int mb = bid % 9, kc = bid / 9;
    const int tid = threadIdx.x, lane = tid & 63, wave = tid >> 6;
    const int wm = wave >> 1, wn = wave & 1;
    const int l15 = lane & 15, g = lane >> 4;

    const size_t kbase = (size_t)kc * 1408 + g * 8;
    const __half* Ap[2];
    #pragma unroll
    for (int mt = 0; mt < 2; ++mt) {
        const int patchm = mb * 128 + wm * 32 + mt * 16 + l15;
        Ap[mt] = h3 + (size_t)patchm * 61952 + kbase;
    }
    const __half* Bp[4];
    #pragma unroll
    for (int nt = 0; nt < 4; ++nt) {
        const int orow = wn * 64 + nt * 16 + l15;
        Bp[nt] = wfh + (size_t)orow * 61952 + kbase;
    }

    f32x4 acc[2][4];
    #pragma unroll
    for (int mt = 0; mt < 2; ++mt)
        #pragma unroll
        for (int nt = 0; nt < 4; ++nt) acc[mt][nt] = (f32x4)0.f;

    #pragma unroll 4
    for (int kk = 0; kk < 44; ++kk) {
        const f16x8 a0 = *reinterpret_cast<const f16x8*>(Ap[0] + kk * 32);
        const f16x8 a1 = *reinterpret_cast<const f16x8*>(Ap[1] + kk * 32);
        f16x8 b[4];
        #pragma unroll
        for (int nt = 0; nt < 4; ++nt)
            b[nt] = *reinterpret_cast<const f16x8*>(Bp[nt] + kk * 32);
        #pragma unroll
        for (int nt = 0; nt < 4; ++nt) {
            acc[0][nt] = __builtin_amdgcn_mfma_f32_16x16x32_f16(a0, b[nt], acc[0][nt], 0, 0, 0);
            acc[1][nt] = __builtin_amdgcn_mfma_f32_16x16x32_f16(a1, b[nt], acc[1][nt], 0, 0, 0);
        }
    }

    #pragma unroll
    for (int mt = 0; mt < 2; ++mt)
        #pragma unroll
        for (int nt = 0; nt < 4; ++nt) {
            const int col = wn * 64 + nt * 16 + l15;
            if (col < 100) {
                #pragma unroll
                for (int r = 0; r < 4; ++r) {
                    const int row = mb * 128 + wm * 32 + mt * 16 + g * 4 + r;
                    atomicAdd(out + (size_t)row * 100 + col, acc[mt][nt][r]);
                }
            }
        }
}

extern "C" void kernel_launch(void* const* d_in, const int* in_sizes, int n_in,
                              void* d_out, int out_size, void* d_ws, size_t ws_size,
                              hipStream_t stream)
{
    const float* x   = (const float*)d_in[0];
    const float* w1  = (const float*)d_in[1];
    const float* b1  = (const float*)d_in[2];
    const float* g1  = (const float*)d_in[3];
    const float* be1 = (const float*)d_in[4];
    const float* m1  = (const float*)d_in[5];
    const float* v1  = (const float*)d_in[6];
    const float* w2  = (const float*)d_in[7];
    const float* b2  = (const float*)d_in[8];
    const float* g2  = (const float*)d_in[9];
    const float* be2 = (const float*)d_in[10];
    const float* m2  = (const float*)d_in[11];
    const float* v2  = (const float*)d_in[12];
    const float* w3  = (const float*)d_in[13];
    const float* b3  = (const float*)d_in[14];
    const float* g3  = (const float*)d_in[15];
    const float* be3 = (const float*)d_in[16];
    const float* m3  = (const float*)d_in[17];
    const float* v3  = (const float*)d_in[18];
    const float* wf  = (const float*)d_in[19];
    const float* bf  = (const float*)d_in[20];

    __half* hws = (__half*)d_ws;     // 155,348,992 B
    float* out = (float*)d_out;

    hipFuncSetAttribute(reinterpret_cast<const void*>(k_conv123),
                        hipFuncAttributeMaxDynamicSharedMemorySize, 163392);

    k_prep<<<6483, 256, 0, stream>>>(w2, w3, wf, hws);
    k_conv123<<<1152, 512, 163392, stream>>>(x, w1, b1, g1, be1, m1, v1,
                                             b2, g2, be2, m2, v2,
                                             b3, g3, be3, m3, v3, hws);
    k_init<<<450, 256, 0, stream>>>(bf, out);
    k_fc<<<396, 512, 0, stream>>>(hws, out);
}